// Round 5
// baseline (368.309 us; speedup 1.0000x reference)
//
#include <hip/hip_runtime.h>

typedef __attribute__((ext_vector_type(8))) short bf16x8;
typedef __attribute__((ext_vector_type(4))) float f32x4;

#define D_IN 256
#define D_OUT 256
#define KDIM 512
#define GM 64

static __device__ __forceinline__ unsigned short f2bf(float f) {
    union { float f; unsigned int u; } x; x.f = f;
    unsigned int r = (x.u + 0x7FFFu + ((x.u >> 16) & 1u)) >> 16;
    return (unsigned short)r;
}

// ---------------- zero deg + pack W fragments (one dispatch) ----------------
// wfrag layout: wf[((nt*16 + kk)*64 + lane)*8 + j] = bf16(W[kk*32 + (lane>>4)*8 + j][nt*16 + (lane&15)])
__global__ void zero_wfrag_kernel(int* __restrict__ deg, int n, int zblocks,
                                  const float* __restrict__ W, unsigned short* __restrict__ wf) {
    int b = blockIdx.x;
    if (b < zblocks) {
        int i = b * 256 + threadIdx.x;
        if (i < n) deg[i] = 0;
    } else {
        int t = (b - zblocks) * 256 + threadIdx.x;
        if (t < 16 * 16 * 64) {
            int l  = t & 63;
            int kk = (t >> 6) & 15;
            int nt = t >> 10;
            int c  = nt * 16 + (l & 15);
            int kb = kk * 32 + (l >> 4) * 8;
            union { unsigned short u[8]; uint4 v; } pk;
#pragma unroll
            for (int j = 0; j < 8; ++j) pk.u[j] = f2bf(W[(size_t)(kb + j) * D_OUT + c]);
            *reinterpret_cast<uint4*>(&wf[(size_t)t * 8]) = pk.v;
        }
    }
}

__global__ void count_kernel(const int* __restrict__ dst, int* __restrict__ deg, int E) {
    int e = blockIdx.x * 256 + threadIdx.x;
    if (e < E) atomicAdd(&deg[dst[e]], 1);
}

// exclusive scan; writes offsets[0..n], cursor[i]=offsets[i], norm[i]=rsqrt(deg)
__global__ void scan_kernel(const int* __restrict__ deg, int* __restrict__ offsets,
                            int* __restrict__ cursor, float* __restrict__ norm, int n) {
    __shared__ int ssum[1024];
    int t = threadIdx.x;
    int C = (n + 1023) >> 10;
    int lo = t * C;
    int hi = lo + C; if (hi > n) hi = n;
    int s = 0;
    for (int i = lo; i < hi; ++i) s += deg[i];
    int v = s;
    ssum[t] = v;
    __syncthreads();
    for (int off = 1; off < 1024; off <<= 1) {
        int u = (t >= off) ? ssum[t - off] : 0;
        __syncthreads();
        v += u;
        ssum[t] = v;
        __syncthreads();
    }
    int run = v - s;   // exclusive prefix
    for (int i = lo; i < hi; ++i) {
        int d = deg[i];
        offsets[i] = run; cursor[i] = run;
        norm[i] = (d > 0) ? rsqrtf((float)d) : 0.0f;
        run += d;
    }
    if (t == 1023) offsets[n] = run;
}

// writes int2{edge_id, src_id}; cursor pre-seeded with offsets -> absolute position
__global__ void scatter_kernel(const int* __restrict__ dst, const int* __restrict__ src_idx,
                               int* __restrict__ cursor, int2* __restrict__ rec, int E) {
    int e = blockIdx.x * 256 + threadIdx.x;
    if (e < E) {
        int p = atomicAdd(&cursor[dst[e]], 1);
        rec[p] = make_int2(e, src_idx[e]);
    }
}

#define ACC8(P) do {                                                    \
    float4 _v0 = *(const float4*)(P);                                   \
    float4 _v1 = *(const float4*)((P) + 4);                             \
    a0.x += _v0.x; a0.y += _v0.y; a0.z += _v0.z; a0.w += _v0.w;         \
    a1.x += _v1.x; a1.y += _v1.y; a1.z += _v1.z; a1.w += _v1.w;         \
} while (0)

// Both shfls execute unconditionally across the full wave (convergent ops must
// not sit inside the lane-divergent ternary); select on the RESULTS.
#define EPTR(Q, P)                                                      \
    int _e_##Q = __shfl(id.x, (P));                                     \
    int _s_##Q = __shfl(id.y, (P));                                     \
    const float* Q = fbase + (size_t)(half ? _e_##Q : _s_##Q) * D_IN

// ---------------- aggregation: one wave per dst row ----------------
__global__ __launch_bounds__(256) void agg_kernel(
    const float* __restrict__ src_feats,
    const float* __restrict__ edge_feats,
    const int2* __restrict__ rec,
    const int* __restrict__ offsets,
    unsigned short* __restrict__ agg,
    int n_dst)
{
    const int wv = threadIdx.x >> 6;
    const int ln = threadIdx.x & 63;
    const int row = blockIdx.x * 4 + wv;
    if (row >= n_dst) return;

    const int half = ln >> 5;            // 0: src half, 1: edge half
    const int sub  = (ln & 31) * 8;      // 8 floats per lane
    const float* fbase = (half ? edge_feats : src_feats) + sub;

    const int s    = offsets[row];
    const int eend = offsets[row + 1];

    float4 a0 = make_float4(0.f, 0.f, 0.f, 0.f);
    float4 a1 = make_float4(0.f, 0.f, 0.f, 0.f);

    for (int c = s; c < eend; c += 64) {
        int cnt = eend - c; if (cnt > 64) cnt = 64;
        int2 id = make_int2(0, 0);
        if (ln < cnt) id = rec[c + ln];
        int p = 0;
        for (; p + 8 <= cnt; p += 8) {
            EPTR(q0, p + 0); EPTR(q1, p + 1); EPTR(q2, p + 2); EPTR(q3, p + 3);
            EPTR(q4, p + 4); EPTR(q5, p + 5); EPTR(q6, p + 6); EPTR(q7, p + 7);
            ACC8(q0); ACC8(q1); ACC8(q2); ACC8(q3);
            ACC8(q4); ACC8(q5); ACC8(q6); ACC8(q7);
        }
        for (; p + 2 <= cnt; p += 2) {
            EPTR(q0, p); EPTR(q1, p + 1);
            ACC8(q0); ACC8(q1);
        }
        for (; p < cnt; ++p) {
            EPTR(q0, p);
            ACC8(q0);
        }
    }

    union { unsigned short u[8]; uint4 v; } pk;
    pk.u[0] = f2bf(a0.x); pk.u[1] = f2bf(a0.y); pk.u[2] = f2bf(a0.z); pk.u[3] = f2bf(a0.w);
    pk.u[4] = f2bf(a1.x); pk.u[5] = f2bf(a1.y); pk.u[6] = f2bf(a1.z); pk.u[7] = f2bf(a1.w);
    // [row][half*256 + (ln&31)*8] == [row][ln*8] -> fully coalesced 1 KB/wave
    *reinterpret_cast<uint4*>(&agg[(size_t)row * KDIM + ln * 8]) = pk.v;
}

// ---------------- GEMM: out[n_dst x 256] = agg[n_dst x 512] @ W + epilogue ----------------
__global__ __launch_bounds__(256) void gemm_kernel(
    const unsigned short* __restrict__ agg,
    const unsigned short* __restrict__ wfrag,
    const float* __restrict__ norm,
    const float* __restrict__ bias,
    float* __restrict__ out,
    int n_dst)
{
    const int wv = threadIdx.x >> 6;
    const int ln = threadIdx.x & 63;
    const int lrow = ln & 15;
    const int lgrp = ln >> 4;
    const int base = blockIdx.x * GM;

    f32x4 acc[4][4];
#pragma unroll
    for (int m = 0; m < 4; ++m)
#pragma unroll
        for (int n = 0; n < 4; ++n) acc[m][n] = (f32x4)(0.0f);

    int rowm[4];
#pragma unroll
    for (int m = 0; m < 4; ++m) {
        int r = base + m * 16 + lrow;
        rowm[m] = (r < n_dst) ? r : (n_dst - 1);   // clamp: reads valid, stores guarded
    }

#pragma unroll
    for (int kk = 0; kk < 16; ++kk) {
        int kb = kk * 32 + lgrp * 8;
        bf16x8 A[4];
#pragma unroll
        for (int m = 0; m < 4; ++m)
            A[m] = *reinterpret_cast<const bf16x8*>(&agg[(size_t)rowm[m] * KDIM + kb]);
#pragma unroll
        for (int n = 0; n < 4; ++n) {
            int nt = wv * 4 + n;
            bf16x8 B = *reinterpret_cast<const bf16x8*>(&wfrag[(((size_t)nt * 16 + kk) * 64 + ln) * 8]);
#pragma unroll
            for (int m = 0; m < 4; ++m)
                acc[m][n] = __builtin_amdgcn_mfma_f32_16x16x32_bf16(A[m], B, acc[m][n], 0, 0, 0);
        }
    }

    float bias_r[4];
#pragma unroll
    for (int n = 0; n < 4; ++n) bias_r[n] = bias[wv * 64 + n * 16 + lrow];

#pragma unroll
    for (int m = 0; m < 4; ++m) {
#pragma unroll
        for (int j = 0; j < 4; ++j) {
            int r = base + m * 16 + lgrp * 4 + j;
            if (r < n_dst) {
                float nv = norm[r];
#pragma unroll
                for (int n = 0; n < 4; ++n)
                    out[(size_t)r * D_OUT + wv * 64 + n * 16 + lrow] = acc[m][n][j] * nv + bias_r[n];
            }
        }
    }
}

extern "C" void kernel_launch(void* const* d_in, const int* in_sizes, int n_in,
                              void* d_out, int out_size, void* d_ws, size_t ws_size,
                              hipStream_t stream) {
    const float* src_feats  = (const float*)d_in[0];
    const float* edge_feats = (const float*)d_in[1];
    const int*   src_idx    = (const int*)d_in[2];
    const int*   dst_idx    = (const int*)d_in[3];
    const float* weights    = (const float*)d_in[4];
    const float* h_bias     = (const float*)d_in[5];

    const int E     = in_sizes[2];
    const int n_dst = out_size / D_OUT;
    float* out = (float*)d_out;

    char* ws = (char*)d_ws;
    size_t agg_bytes = (size_t)n_dst * KDIM * 2;            // 51.2 MB
    unsigned short* agg   = (unsigned short*)ws;
    unsigned short* wfrag = (unsigned short*)(ws + agg_bytes);         // 262144 B
    int2* rec     = (int2*)(ws + agg_bytes + 262144);                  // E * 8 B
    int*  deg     = (int*)(ws + agg_bytes + 262144 + (size_t)E * 8);
    int*  offsets = deg + n_dst;                            // n_dst + 1
    int*  cursor  = offsets + n_dst + 1;                    // n_dst
    float* norm   = (float*)(cursor + n_dst);               // n_dst

    const int CB = (E + 255) / 256;
    const int ZB = (n_dst + 255) / 256;

    zero_wfrag_kernel<<<ZB + 64, 256, 0, stream>>>(deg, n_dst, ZB, weights, wfrag);
    count_kernel<<<CB, 256, 0, stream>>>(dst_idx, deg, E);
    scan_kernel<<<1, 1024, 0, stream>>>(deg, offsets, cursor, norm, n_dst);
    scatter_kernel<<<CB, 256, 0, stream>>>(dst_idx, src_idx, cursor, rec, E);

    agg_kernel<<<(n_dst + 3) / 4, 256, 0, stream>>>(
        src_feats, edge_feats, rec, offsets, agg, n_dst);
    gemm_kernel<<<(n_dst + GM - 1) / GM, 256, 0, stream>>>(
        agg, wfrag, norm, h_bias, out, n_dst);
}

// Round 6
// 266.758 us; speedup vs baseline: 1.3807x; 1.3807x over previous
//
#include <hip/hip_runtime.h>

typedef __attribute__((ext_vector_type(8))) short bf16x8;
typedef __attribute__((ext_vector_type(4))) float f32x4;

#define D_IN 256
#define D_OUT 256
#define KDIM 512
#define GM 64
#define G_ROWS 8           // dst rows per wave in agg
#define CHUNK 4            // edges per pipeline chunk (2 KB each)
#define SCAN_BLOCKS 256

static __device__ __forceinline__ unsigned short f2bf(float f) {
    union { float f; unsigned int u; } x; x.f = f;
    unsigned int r = (x.u + 0x7FFFu + ((x.u >> 16) & 1u)) >> 16;
    return (unsigned short)r;
}

// async global->LDS, 16B per lane; LDS dest = uniform base + lane*16
#define GLOAD16(gp, lp) __builtin_amdgcn_global_load_lds(                    \
    (const __attribute__((address_space(1))) void*)(gp),                     \
    (__attribute__((address_space(3))) void*)(lp), 16, 0, 0)

// ---------------- zero deg + pack W fragments ----------------
// wfrag: wf[((nt*16 + kk)*64 + lane)*8 + j] = bf16(W[kk*32 + (lane>>4)*8 + j][nt*16 + (lane&15)])
__global__ void zero_wfrag_kernel(int* __restrict__ deg, int n, int zblocks,
                                  const float* __restrict__ W, unsigned short* __restrict__ wf) {
    int b = blockIdx.x;
    if (b < zblocks) {
        int i = b * 256 + threadIdx.x;
        if (i < n) deg[i] = 0;
    } else {
        int t = (b - zblocks) * 256 + threadIdx.x;
        if (t < 16 * 16 * 64) {
            int l  = t & 63;
            int kk = (t >> 6) & 15;
            int nt = t >> 10;
            int c  = nt * 16 + (l & 15);
            int kb = kk * 32 + (l >> 4) * 8;
            union { unsigned short u[8]; uint4 v; } pk;
#pragma unroll
            for (int j = 0; j < 8; ++j) pk.u[j] = f2bf(W[(size_t)(kb + j) * D_OUT + c]);
            *reinterpret_cast<uint4*>(&wf[(size_t)t * 8]) = pk.v;
        }
    }
}

__global__ void count_kernel(const int* __restrict__ dst, int* __restrict__ deg, int E) {
    int e = blockIdx.x * 256 + threadIdx.x;
    if (e < E) atomicAdd(&deg[dst[e]], 1);
}

// ---------------- multi-block scan (2 kernels) ----------------
__global__ void scan_part_kernel(const int* __restrict__ deg, int* __restrict__ part, int n) {
    __shared__ int red[256];
    int b = blockIdx.x, t = threadIdx.x;
    int per = (n + SCAN_BLOCKS - 1) / SCAN_BLOCKS;
    int lo = b * per;
    int hi = lo + per; if (hi > n) hi = n;
    int s = 0;
    for (int i = lo + t; i < hi; i += 256) s += deg[i];
    red[t] = s;
    __syncthreads();
    for (int o = 128; o > 0; o >>= 1) {
        if (t < o) red[t] += red[t + o];
        __syncthreads();
    }
    if (t == 0) part[b] = red[0];
}

__global__ void scan_emit_kernel(const int* __restrict__ deg, const int* __restrict__ part,
                                 int* __restrict__ offsets, int* __restrict__ cursor,
                                 float* __restrict__ norm, int n) {
    int b = blockIdx.x, t = threadIdx.x;   // 64 threads = 1 wave
    int per = (n + SCAN_BLOCKS - 1) / SCAN_BLOCKS;
    int lo = b * per;
    int hi = lo + per; if (hi > n) hi = n;
    // base = sum part[0..b)
    int v = 0;
    for (int i = t; i < b; i += 64) v += part[i];
#pragma unroll
    for (int o = 32; o > 0; o >>= 1) v += __shfl_down(v, o);
    int base = __shfl(v, 0);
    // lane sub-ranges
    int sub = (per + 63) / 64;
    int llo = lo + t * sub;
    int lhi = llo + sub;
    if (lhi > hi) lhi = hi;
    if (llo > hi) llo = hi;
    int s = 0;
    for (int i = llo; i < lhi; ++i) s += deg[i];
    int incl = s;
#pragma unroll
    for (int o = 1; o < 64; o <<= 1) { int u = __shfl_up(incl, o); if (t >= o) incl += u; }
    int run = base + incl - s;             // exclusive prefix for this lane
    for (int i = llo; i < lhi; ++i) {
        int d = deg[i];
        offsets[i] = run; cursor[i] = run;
        norm[i] = (d > 0) ? rsqrtf((float)d) : 0.0f;
        run += d;
    }
    if (b == SCAN_BLOCKS - 1 && t == 63) offsets[n] = base + incl;
}

// writes int2{edge_id, src_id}; cursor pre-seeded with offsets
__global__ void scatter_kernel(const int* __restrict__ dst, const int* __restrict__ src_idx,
                               int* __restrict__ cursor, int2* __restrict__ rec, int E) {
    int e = blockIdx.x * 256 + threadIdx.x;
    if (e < E) {
        int p = atomicAdd(&cursor[dst[e]], 1);
        rec[p] = make_int2(e, src_idx[e]);
    }
}

// ---------------- aggregation: LDS-staged, counted-vmcnt pipeline ----------------
// Each wave owns G_ROWS consecutive dst rows = a contiguous edge range in rec.
// Edges stream through LDS in CHUNK-sized groups, 2 chunks in flight (16 ops),
// consumed with s_waitcnt vmcnt(8). Tails padded with dummy loads of row 0.
__global__ __launch_bounds__(256) void agg_kernel(
    const float* __restrict__ src_feats,
    const float* __restrict__ edge_feats,
    const int2* __restrict__ rec,
    const int* __restrict__ offsets,
    unsigned short* __restrict__ agg,
    int n_dst)
{
    __shared__ __align__(16) float lds[4][2][CHUNK][KDIM];   // 64 KB

    const int wv = threadIdx.x >> 6;
    const int ln = threadIdx.x & 63;
    const int rowbase = (blockIdx.x * 4 + wv) * G_ROWS;

    // offsets for rows rowbase..rowbase+G_ROWS (lanes 0..G_ROWS), clamped
    int off_l;
    {
        int k = (ln <= G_ROWS) ? ln : G_ROWS;
        int i = rowbase + k;
        if (i > n_dst) i = n_dst;
        off_l = offsets[i];
    }
    const int s   = __shfl(off_l, 0);
    const int nE  = __shfl(off_l, G_ROWS) - s;
    const int nCh = (nE + CHUNK - 1) / CHUNK;

    // id window: covers edges [win, win+64)
    int win = 0;
    int2 idw = make_int2(0, 0);
    if (ln < nE) idw = rec[s + ln];

    auto issue_chunk = [&](int ci) {
        int buf = ci & 1;
        int e0 = ci * CHUNK;
        if (e0 < nE && e0 + CHUNK - 1 >= win + 64) {      // refill window
            win = e0;
            int rem = nE - win;
            idw = make_int2(0, 0);
            if (ln < rem) idw = rec[s + win + ln];
        }
#pragma unroll
        for (int t = 0; t < CHUNK; ++t) {
            int j = e0 + t;
            int rel = (j - win) & 63;
            int ex = __shfl(idw.x, rel);                   // edge id
            int sx = __shfl(idw.y, rel);                   // src id
            int sid = 0, eid = 0;
            if (j < nE) { sid = sx; eid = ex; }
            float* lp = &lds[wv][buf][t][0];
            GLOAD16(src_feats  + (size_t)sid * D_IN + ln * 4, lp);
            GLOAD16(edge_feats + (size_t)eid * D_IN + ln * 4, lp + D_IN);
        }
    };

    float4 a0 = make_float4(0.f, 0.f, 0.f, 0.f);
    float4 a1 = make_float4(0.f, 0.f, 0.f, 0.f);
    int curRow = 0;
    int curEndRel = __shfl(off_l, 1) - s;

    auto flush = [&]() {
        int gr = rowbase + curRow;
        if (gr < n_dst) {
            ushort4 p0, p1;
            p0.x = f2bf(a0.x); p0.y = f2bf(a0.y); p0.z = f2bf(a0.z); p0.w = f2bf(a0.w);
            p1.x = f2bf(a1.x); p1.y = f2bf(a1.y); p1.z = f2bf(a1.z); p1.w = f2bf(a1.w);
            *reinterpret_cast<ushort4*>(&agg[(size_t)gr * KDIM + ln * 4]) = p0;
            *reinterpret_cast<ushort4*>(&agg[(size_t)gr * KDIM + D_IN + ln * 4]) = p1;
        }
        a0 = make_float4(0.f, 0.f, 0.f, 0.f);
        a1 = make_float4(0.f, 0.f, 0.f, 0.f);
    };

    issue_chunk(0);
    issue_chunk(1);

    for (int ci = 0; ci < nCh; ++ci) {
        asm volatile("s_waitcnt vmcnt(8)" ::: "memory");   // chunk ci's 8 ops complete
        __builtin_amdgcn_sched_barrier(0);
        int buf = ci & 1;
        int e0 = ci * CHUNK;
#pragma unroll
        for (int t = 0; t < CHUNK; ++t) {
            int j = e0 + t;
            if (j >= nE) break;                            // uniform
            while (j >= curEndRel) {                       // row boundary (uniform)
                flush();
                ++curRow;
                curEndRel = __shfl(off_l, curRow + 1) - s;
            }
            float4 v0 = *reinterpret_cast<const float4*>(&lds[wv][buf][t][ln * 4]);
            float4 v1 = *reinterpret_cast<const float4*>(&lds[wv][buf][t][D_IN + ln * 4]);
            a0.x += v0.x; a0.y += v0.y; a0.z += v0.z; a0.w += v0.w;
            a1.x += v1.x; a1.y += v1.y; a1.z += v1.z; a1.w += v1.w;
        }
        issue_chunk(ci + 2);                               // keeps 16 ops outstanding
    }
    while (curRow < G_ROWS) { flush(); ++curRow; }
    asm volatile("s_waitcnt vmcnt(0)" ::: "memory");       // drain before LDS dealloc
}

// ---------------- GEMM: out[n_dst x 256] = agg[n_dst x 512] @ W + epilogue ----------------
__global__ __launch_bounds__(256) void gemm_kernel(
    const unsigned short* __restrict__ agg,
    const unsigned short* __restrict__ wfrag,
    const float* __restrict__ norm,
    const float* __restrict__ bias,
    float* __restrict__ out,
    int n_dst)
{
    const int wv = threadIdx.x >> 6;
    const int ln = threadIdx.x & 63;
    const int lrow = ln & 15;
    const int lgrp = ln >> 4;
    const int base = blockIdx.x * GM;

    f32x4 acc[4][4];
#pragma unroll
    for (int m = 0; m < 4; ++m)
#pragma unroll
        for (int n = 0; n < 4; ++n) acc[m][n] = (f32x4)(0.0f);

    int rowm[4];
#pragma unroll
    for (int m = 0; m < 4; ++m) {
        int r = base + m * 16 + lrow;
        rowm[m] = (r < n_dst) ? r : (n_dst - 1);
    }

#pragma unroll
    for (int kk = 0; kk < 16; ++kk) {
        int kb = kk * 32 + lgrp * 8;
        bf16x8 A[4];
#pragma unroll
        for (int m = 0; m < 4; ++m)
            A[m] = *reinterpret_cast<const bf16x8*>(&agg[(size_t)rowm[m] * KDIM + kb]);
#pragma unroll
        for (int n = 0; n < 4; ++n) {
            int nt = wv * 4 + n;
            bf16x8 B = *reinterpret_cast<const bf16x8*>(&wfrag[(((size_t)nt * 16 + kk) * 64 + ln) * 8]);
#pragma unroll
            for (int m = 0; m < 4; ++m)
                acc[m][n] = __builtin_amdgcn_mfma_f32_16x16x32_bf16(A[m], B, acc[m][n], 0, 0, 0);
        }
    }

    float bias_r[4];
#pragma unroll
    for (int n = 0; n < 4; ++n) bias_r[n] = bias[wv * 64 + n * 16 + lrow];

#pragma unroll
    for (int m = 0; m < 4; ++m) {
#pragma unroll
        for (int j = 0; j < 4; ++j) {
            int r = base + m * 16 + lgrp * 4 + j;
            if (r < n_dst) {
                float nv = norm[r];
#pragma unroll
                for (int n = 0; n < 4; ++n)
                    out[(size_t)r * D_OUT + wv * 64 + n * 16 + lrow] = acc[m][n][j] * nv + bias_r[n];
            }
        }
    }
}

extern "C" void kernel_launch(void* const* d_in, const int* in_sizes, int n_in,
                              void* d_out, int out_size, void* d_ws, size_t ws_size,
                              hipStream_t stream) {
    const float* src_feats  = (const float*)d_in[0];
    const float* edge_feats = (const float*)d_in[1];
    const int*   src_idx    = (const int*)d_in[2];
    const int*   dst_idx    = (const int*)d_in[3];
    const float* weights    = (const float*)d_in[4];
    const float* h_bias     = (const float*)d_in[5];

    const int E     = in_sizes[2];
    const int n_dst = out_size / D_OUT;
    float* out = (float*)d_out;

    char* ws = (char*)d_ws;
    size_t agg_bytes = (size_t)n_dst * KDIM * 2;                       // 51.2 MB
    unsigned short* agg   = (unsigned short*)ws;
    unsigned short* wfrag = (unsigned short*)(ws + agg_bytes);         // 262144 B
    int2* rec     = (int2*)(ws + agg_bytes + 262144);                  // E * 8 B
    int*  deg     = (int*)(ws + agg_bytes + 262144 + (size_t)E * 8);
    int*  offsets = deg + n_dst;                                       // n_dst + 1
    int*  cursor  = offsets + n_dst + 1;                               // n_dst
    float* norm   = (float*)(cursor + n_dst);                          // n_dst
    int*  part    = (int*)(norm + n_dst);                              // SCAN_BLOCKS

    const int CB = (E + 255) / 256;
    const int ZB = (n_dst + 255) / 256;

    zero_wfrag_kernel<<<ZB + 64, 256, 0, stream>>>(deg, n_dst, ZB, weights, wfrag);
    count_kernel<<<CB, 256, 0, stream>>>(dst_idx, deg, E);
    scan_part_kernel<<<SCAN_BLOCKS, 256, 0, stream>>>(deg, part, n_dst);
    scan_emit_kernel<<<SCAN_BLOCKS, 64, 0, stream>>>(deg, part, offsets, cursor, norm, n_dst);
    scatter_kernel<<<CB, 256, 0, stream>>>(dst_idx, src_idx, cursor, rec, E);

    agg_kernel<<<(n_dst + 4 * G_ROWS - 1) / (4 * G_ROWS), 256, 0, stream>>>(
        src_feats, edge_feats, rec, offsets, agg, n_dst);
    gemm_kernel<<<(n_dst + GM - 1) / GM, 256, 0, stream>>>(
        agg, wfrag, norm, h_bias, out, n_dst);
}

// Round 7
// 237.779 us; speedup vs baseline: 1.5490x; 1.1219x over previous
//
#include <hip/hip_runtime.h>

typedef __attribute__((ext_vector_type(8))) short bf16x8;
typedef __attribute__((ext_vector_type(4))) float f32x4;

#define D_IN 256
#define D_OUT 256
#define KDIM 512
#define GM 64
#define G_ROWS 8           // dst rows per wave in agg
#define CHUNK 2            // edges per pipeline chunk (2 KB each)
#define IDCAP 128          // ids staged per segment (per wave)
#define SCAN_BLOCKS 256

static __device__ __forceinline__ unsigned short f2bf(float f) {
    union { float f; unsigned int u; } x; x.f = f;
    unsigned int r = (x.u + 0x7FFFu + ((x.u >> 16) & 1u)) >> 16;
    return (unsigned short)r;
}

// async global->LDS: lds dest = UNIFORM base (HW adds lane*16); global src = per-lane
#define GLOAD16(gp, lp) __builtin_amdgcn_global_load_lds(                    \
    (const __attribute__((address_space(1))) void*)(gp),                     \
    (__attribute__((address_space(3))) void*)(lp), 16, 0, 0)

// ---------------- zero deg + pack W fragments ----------------
// wfrag: wf[((nt*16 + kk)*64 + lane)*8 + j] = bf16(W[kk*32 + (lane>>4)*8 + j][nt*16 + (lane&15)])
__global__ void zero_wfrag_kernel(int* __restrict__ deg, int n, int zblocks,
                                  const float* __restrict__ W, unsigned short* __restrict__ wf) {
    int b = blockIdx.x;
    if (b < zblocks) {
        int i = b * 256 + threadIdx.x;
        if (i < n) deg[i] = 0;
    } else {
        int t = (b - zblocks) * 256 + threadIdx.x;
        if (t < 16 * 16 * 64) {
            int l  = t & 63;
            int kk = (t >> 6) & 15;
            int nt = t >> 10;
            int c  = nt * 16 + (l & 15);
            int kb = kk * 32 + (l >> 4) * 8;
            union { unsigned short u[8]; uint4 v; } pk;
#pragma unroll
            for (int j = 0; j < 8; ++j) pk.u[j] = f2bf(W[(size_t)(kb + j) * D_OUT + c]);
            *reinterpret_cast<uint4*>(&wf[(size_t)t * 8]) = pk.v;
        }
    }
}

__global__ void count_kernel(const int* __restrict__ dst, int* __restrict__ deg, int E) {
    int e = blockIdx.x * 256 + threadIdx.x;
    if (e < E) atomicAdd(&deg[dst[e]], 1);
}

// ---------------- multi-block scan (2 kernels) ----------------
__global__ void scan_part_kernel(const int* __restrict__ deg, int* __restrict__ part, int n) {
    __shared__ int red[256];
    int b = blockIdx.x, t = threadIdx.x;
    int per = (n + SCAN_BLOCKS - 1) / SCAN_BLOCKS;
    int lo = b * per;
    int hi = lo + per; if (hi > n) hi = n;
    int s = 0;
    for (int i = lo + t; i < hi; i += 256) s += deg[i];
    red[t] = s;
    __syncthreads();
    for (int o = 128; o > 0; o >>= 1) {
        if (t < o) red[t] += red[t + o];
        __syncthreads();
    }
    if (t == 0) part[b] = red[0];
}

__global__ void scan_emit_kernel(const int* __restrict__ deg, const int* __restrict__ part,
                                 int* __restrict__ offsets, int* __restrict__ cursor,
                                 float* __restrict__ norm, int n) {
    int b = blockIdx.x, t = threadIdx.x;   // 64 threads = 1 wave
    int per = (n + SCAN_BLOCKS - 1) / SCAN_BLOCKS;
    int lo = b * per;
    int hi = lo + per; if (hi > n) hi = n;
    int v = 0;
    for (int i = t; i < b; i += 64) v += part[i];
#pragma unroll
    for (int o = 32; o > 0; o >>= 1) v += __shfl_down(v, o);
    int base = __shfl(v, 0);
    int sub = (per + 63) / 64;
    int llo = lo + t * sub;
    int lhi = llo + sub;
    if (lhi > hi) lhi = hi;
    if (llo > hi) llo = hi;
    int s = 0;
    for (int i = llo; i < lhi; ++i) s += deg[i];
    int incl = s;
#pragma unroll
    for (int o = 1; o < 64; o <<= 1) { int u = __shfl_up(incl, o); if (t >= o) incl += u; }
    int run = base + incl - s;
    for (int i = llo; i < lhi; ++i) {
        int d = deg[i];
        offsets[i] = run; cursor[i] = run;
        norm[i] = (d > 0) ? rsqrtf((float)d) : 0.0f;
        run += d;
    }
    if (b == SCAN_BLOCKS - 1 && t == 63) offsets[n] = base + incl;
}

__global__ void scatter_kernel(const int* __restrict__ dst, const int* __restrict__ src_idx,
                               int* __restrict__ cursor, int2* __restrict__ rec, int E) {
    int e = blockIdx.x * 256 + threadIdx.x;
    if (e < E) {
        int p = atomicAdd(&cursor[dst[e]], 1);
        rec[p] = make_int2(e, src_idx[e]);
    }
}

// ---------------- aggregation: LDS-staged features AND ids, counted-vmcnt ----------------
// Wave owns G_ROWS consecutive rows = contiguous edge range. Ids go global->LDS once
// per segment (one vmcnt(0)), then per-chunk id reads are uniform ds_read (lgkmcnt only,
// no vmcnt drain). Features: 2-deep chunk pipeline, wait vmcnt(4), never 0 in loop.
__global__ __launch_bounds__(256) void agg_kernel(
    const float* __restrict__ src_feats,
    const float* __restrict__ edge_feats,
    const int2* __restrict__ rec,
    const int* __restrict__ offsets,
    unsigned short* __restrict__ agg,
    int n_dst)
{
    __shared__ __align__(16) float fb[4][2][CHUNK][KDIM];   // 4*2*2*2KB = 32 KB
    __shared__ __align__(16) int2 idb[4][IDCAP + 128];      // 8 KB (staging pad incl.)

    const int wv = threadIdx.x >> 6;
    const int ln = threadIdx.x & 63;
    const int rowbase = (blockIdx.x * 4 + wv) * G_ROWS;

    int off_l;
    {
        int k = (ln <= G_ROWS) ? ln : G_ROWS;
        int i = rowbase + k;
        if (i > n_dst) i = n_dst;
        off_l = offsets[i];
    }
    const int s  = __shfl(off_l, 0);
    const int nE = __shfl(off_l, G_ROWS) - s;

    float4 a0 = make_float4(0.f, 0.f, 0.f, 0.f);
    float4 a1 = make_float4(0.f, 0.f, 0.f, 0.f);
    int curRow = 0;
    int curEnd = __shfl(off_l, 1) - s;

    auto flush = [&]() {
        int gr = rowbase + curRow;
        if (gr < n_dst) {
            ushort4 p0, p1;
            p0.x = f2bf(a0.x); p0.y = f2bf(a0.y); p0.z = f2bf(a0.z); p0.w = f2bf(a0.w);
            p1.x = f2bf(a1.x); p1.y = f2bf(a1.y); p1.z = f2bf(a1.z); p1.w = f2bf(a1.w);
            *reinterpret_cast<ushort4*>(&agg[(size_t)gr * KDIM + ln * 4]) = p0;
            *reinterpret_cast<ushort4*>(&agg[(size_t)gr * KDIM + D_IN + ln * 4]) = p1;
        }
        a0 = make_float4(0.f, 0.f, 0.f, 0.f);
        a1 = make_float4(0.f, 0.f, 0.f, 0.f);
    };

    for (int g0 = 0; g0 < nE; g0 += IDCAP) {
        int segN = nE - g0; if (segN > IDCAP) segN = IDCAP;
        const int sg = s + g0;
        const int base16 = sg & ~1;                 // 16B-aligned source start
        const int extra = sg - base16;
        const int idops = ((segN + extra) * 8 + 1023) >> 10;   // <=2 for IDCAP=128
        for (int o = 0; o < idops; ++o)
            GLOAD16((const char*)(rec + base16) + o * 1024 + ln * 16,
                    (char*)&idb[wv][0] + o * 1024);
        asm volatile("s_waitcnt vmcnt(0)" ::: "memory");
        __builtin_amdgcn_sched_barrier(0);

        const int nCh = (segN + CHUNK - 1) / CHUNK;

        auto issue = [&](int ci) {
            int buf = ci & 1;
            int e0 = ci * CHUNK;
#pragma unroll
            for (int t = 0; t < CHUNK; ++t) {
                int j = e0 + t;
                int sid = 0, eid = 0;
                if (j < segN) { int2 v = idb[wv][j + extra]; eid = v.x; sid = v.y; }
                float* lp = &fb[wv][buf][t][0];
                GLOAD16(src_feats  + (size_t)sid * D_IN + ln * 4, lp);
                GLOAD16(edge_feats + (size_t)eid * D_IN + ln * 4, lp + D_IN);
            }
        };

        issue(0); issue(1);
        for (int ci = 0; ci < nCh; ++ci) {
            asm volatile("s_waitcnt vmcnt(4)" ::: "memory");   // chunk ci landed; ci+1 in flight
            __builtin_amdgcn_sched_barrier(0);
            int buf = ci & 1;
            int e0 = ci * CHUNK;
#pragma unroll
            for (int t = 0; t < CHUNK; ++t) {
                int j = e0 + t;
                if (j >= segN) break;                          // uniform
                int ja = g0 + j;
                while (ja >= curEnd) {                         // row boundary (uniform)
                    flush();
                    ++curRow;
                    curEnd = __shfl(off_l, curRow + 1) - s;
                }
                float4 v0 = *reinterpret_cast<const float4*>(&fb[wv][buf][t][ln * 4]);
                float4 v1 = *reinterpret_cast<const float4*>(&fb[wv][buf][t][D_IN + ln * 4]);
                a0.x += v0.x; a0.y += v0.y; a0.z += v0.z; a0.w += v0.w;
                a1.x += v1.x; a1.y += v1.y; a1.z += v1.z; a1.w += v1.w;
            }
            issue(ci + 2);
        }
        asm volatile("s_waitcnt vmcnt(0)" ::: "memory");       // drain before idb/fb reuse or exit
        __builtin_amdgcn_sched_barrier(0);
    }
    while (curRow < G_ROWS) { flush(); ++curRow; }
}

// ---------------- GEMM: LDS-staged A (coalesced GLOAD16, XOR-swizzled granules) ----------------
__global__ __launch_bounds__(256) void gemm_kernel(
    const unsigned short* __restrict__ agg,
    const unsigned short* __restrict__ wfrag,
    const float* __restrict__ norm,
    const float* __restrict__ bias,
    float* __restrict__ out,
    int n_dst)
{
    __shared__ __align__(16) unsigned short As[GM * KDIM];   // 64 KB

    const int wv = threadIdx.x >> 6;
    const int ln = threadIdx.x & 63;
    const int lrow = ln & 15;
    const int lgrp = ln >> 4;
    const int base = blockIdx.x * GM;

    // stage A: row r (1 KB) = one GLOAD16 per wave; source granule pre-inverse-swizzled
    for (int r = wv; r < GM; r += 4) {
        int gr = base + r; if (gr >= n_dst) gr = n_dst - 1;
        GLOAD16(agg + (size_t)gr * KDIM + (size_t)((ln ^ (r & 7)) * 8),
                (char*)As + r * 1024);
    }
    asm volatile("s_waitcnt vmcnt(0)" ::: "memory");
    __syncthreads();

    f32x4 acc[4][4];
#pragma unroll
    for (int m = 0; m < 4; ++m)
#pragma unroll
        for (int n = 0; n < 4; ++n) acc[m][n] = (f32x4)(0.0f);

#pragma unroll
    for (int kk = 0; kk < 16; ++kk) {
        bf16x8 A[4];
#pragma unroll
        for (int m = 0; m < 4; ++m) {
            int r = m * 16 + lrow;
            int g = (kk * 4 + lgrp) ^ (r & 7);               // swizzled granule
            A[m] = *reinterpret_cast<const bf16x8*>((const char*)As + r * 1024 + g * 16);
        }
#pragma unroll
        for (int n = 0; n < 4; ++n) {
            int nt = wv * 4 + n;
            bf16x8 B = *reinterpret_cast<const bf16x8*>(&wfrag[(((size_t)nt * 16 + kk) * 64 + ln) * 8]);
#pragma unroll
            for (int m = 0; m < 4; ++m)
                acc[m][n] = __builtin_amdgcn_mfma_f32_16x16x32_bf16(A[m], B, acc[m][n], 0, 0, 0);
        }
    }

    float bias_r[4];
#pragma unroll
    for (int n = 0; n < 4; ++n) bias_r[n] = bias[wv * 64 + n * 16 + lrow];

#pragma unroll
    for (int m = 0; m < 4; ++m) {
#pragma unroll
        for (int j = 0; j < 4; ++j) {
            int r = base + m * 16 + lgrp * 4 + j;
            if (r < n_dst) {
                float nv = norm[r];
#pragma unroll
                for (int n = 0; n < 4; ++n)
                    out[(size_t)r * D_OUT + wv * 64 + n * 16 + lrow] = acc[m][n][j] * nv + bias_r[n];
            }
        }
    }
}

extern "C" void kernel_launch(void* const* d_in, const int* in_sizes, int n_in,
                              void* d_out, int out_size, void* d_ws, size_t ws_size,
                              hipStream_t stream) {
    const float* src_feats  = (const float*)d_in[0];
    const float* edge_feats = (const float*)d_in[1];
    const int*   src_idx    = (const int*)d_in[2];
    const int*   dst_idx    = (const int*)d_in[3];
    const float* weights    = (const float*)d_in[4];
    const float* h_bias     = (const float*)d_in[5];

    const int E     = in_sizes[2];
    const int n_dst = out_size / D_OUT;
    float* out = (float*)d_out;

    char* ws = (char*)d_ws;
    size_t agg_bytes = (size_t)n_dst * KDIM * 2;                       // 51.2 MB
    unsigned short* agg   = (unsigned short*)ws;
    unsigned short* wfrag = (unsigned short*)(ws + agg_bytes);         // 262144 B
    int2* rec     = (int2*)(ws + agg_bytes + 262144);                  // E*8 B + 2 KB pad
    char* after_rec = ws + agg_bytes + 262144 + (size_t)E * 8 + 2048;
    int*  deg     = (int*)after_rec;
    int*  offsets = deg + n_dst;                                       // n_dst + 1
    int*  cursor  = offsets + n_dst + 1;                               // n_dst
    float* norm   = (float*)(cursor + n_dst);                          // n_dst
    int*  part    = (int*)(norm + n_dst);                              // SCAN_BLOCKS

    const int CB = (E + 255) / 256;
    const int ZB = (n_dst + 255) / 256;

    zero_wfrag_kernel<<<ZB + 64, 256, 0, stream>>>(deg, n_dst, ZB, weights, wfrag);
    count_kernel<<<CB, 256, 0, stream>>>(dst_idx, deg, E);
    scan_part_kernel<<<SCAN_BLOCKS, 256, 0, stream>>>(deg, part, n_dst);
    scan_emit_kernel<<<SCAN_BLOCKS, 64, 0, stream>>>(deg, part, offsets, cursor, norm, n_dst);
    scatter_kernel<<<CB, 256, 0, stream>>>(dst_idx, src_idx, cursor, rec, E);

    agg_kernel<<<(n_dst + 4 * G_ROWS - 1) / (4 * G_ROWS), 256, 0, stream>>>(
        src_feats, edge_feats, rec, offsets, agg, n_dst);
    gemm_kernel<<<(n_dst + GM - 1) / GM, 256, 0, stream>>>(
        agg, wfrag, norm, h_bias, out, n_dst);
}